// Round 6
// baseline (201.353 us; speedup 1.0000x reference)
//
#include <hip/hip_runtime.h>
#include <stdint.h>

#define S_LEN 2048
#define D_DIM 64
#define NBH   32
#define TQ    128
#define KT    64
#define NT    (S_LEN / KT)
#define RC_G  4
#define SCALE_F 0.125f
#define EPS_F   1e-6f
#define SPSTR 40   /* sP row stride in shorts: 80B, 16B-aligned rows */

typedef unsigned short us;
typedef __attribute__((ext_vector_type(8))) short bf8_t;
typedef __attribute__((ext_vector_type(4))) float f4_t;
typedef __attribute__((ext_vector_type(16))) float f16_t;
typedef __attribute__((ext_vector_type(4))) unsigned int u4_t;

#define MFMA16(a,b,c) __builtin_amdgcn_mfma_f32_16x16x32_bf16((a),(b),(c),0,0,0)
#define MFMA32(a,b,c) __builtin_amdgcn_mfma_f32_32x32x16_bf16((a),(b),(c),0,0,0)

__device__ __forceinline__ unsigned int cvtpk(float lo, float hi) {
  unsigned int d;
  asm("v_cvt_pk_bf16_f32 %0, %1, %2" : "=v"(d) : "v"(lo), "v"(hi));
  return d;
}

union u4bf8 { u4_t u; bf8_t b; };

// ---------------- G partials: gpart[rc][bh][64*64], no atomics ----------------
__global__ __launch_bounds__(256) void g_kernel(const float* __restrict__ kp,
                                                float* __restrict__ gpart) {
  __shared__ __align__(16) float sk[64][68];
  const int bh = blockIdx.x >> 2, rc = blockIdx.x & 3;
  const int t = threadIdx.x;
  const int ti = t >> 4, tj = t & 15;   // ti=row-patch, tj=col-patch (tj fast => coalesced stores)
  float acc[4][4];
#pragma unroll
  for (int a = 0; a < 4; ++a)
#pragma unroll
    for (int b = 0; b < 4; ++b) acc[a][b] = 0.f;
  const float* kb = kp + ((size_t)bh * S_LEN + rc * 512) * D_DIM;
  for (int sub = 0; sub < 8; ++sub) {
    __syncthreads();
    {
      const int r = t >> 2, c0 = (t & 3) * 16;
      const float4* p = (const float4*)(kb + (size_t)(sub * 64 + r) * D_DIM + c0);
      float4 x0 = p[0], x1 = p[1], x2 = p[2], x3 = p[3];
      *(float4*)&sk[r][c0]      = x0;
      *(float4*)&sk[r][c0 + 4]  = x1;
      *(float4*)&sk[r][c0 + 8]  = x2;
      *(float4*)&sk[r][c0 + 12] = x3;
    }
    __syncthreads();
#pragma unroll 4
    for (int r = 0; r < 64; ++r) {
      float4 qi = *(const float4*)&sk[r][ti * 4];
      float4 qj = *(const float4*)&sk[r][tj * 4];
      float iv[4] = {qi.x, qi.y, qi.z, qi.w};
      float jv[4] = {qj.x, qj.y, qj.z, qj.w};
#pragma unroll
      for (int a = 0; a < 4; ++a)
#pragma unroll
        for (int b = 0; b < 4; ++b) acc[a][b] += iv[a] * jv[b];
    }
  }
  float* gb = gpart + ((size_t)(rc * NBH + bh) << 12);
#pragma unroll
  for (int a = 0; a < 4; ++a) {
    f4_t vv = {acc[a][0], acc[a][1], acc[a][2], acc[a][3]};
    *(f4_t*)(gb + (ti * 4 + a) * 64 + tj * 4) = vv;
  }
}

// swizzled row-major bf16 tile: row stride 64 shorts, 16B chunks XOR'd by row&7
__device__ __forceinline__ bf8_t frag_swz(const us* sp, int row, int cb) {
  return *(const bf8_t*)(sp + row * 64 + ((cb ^ (row & 7)) << 3));
}

// ---------------- main attention kernel ----------------
__global__ __launch_bounds__(512, 4) void attn_main(const float* __restrict__ q,
                                                    const float* __restrict__ k,
                                                    const float* __restrict__ v,
                                                    const float* __restrict__ gpart,
                                                    float* __restrict__ outp,
                                                    float* __restrict__ probp) {
  // smem: sK 2x8KB | sVt 2x8KB | sP 8 waves * 2560B = 20480B  (total 53248)
  // sInv(512B) overlaps sP start (used only before main loop)
  // sRed(32KB) overlaps sK (used only in epilogue)
  __shared__ __align__(16) unsigned char smem[53248];
  us* sK  = (us*)smem;                 // 2 buffers of 4096 shorts
  us* sVt = (us*)(smem + 16384);       // 2 buffers of 4096 shorts
  us* sP  = (us*)(smem + 32768);
  float* sInv = (float*)(smem + 32768);
  float* sRed = (float*)smem;

  const int lin = blockIdx.x;
  const int virt = (lin & 7) * 64 + (lin >> 3);   // XCD swizzle (512 = 8*64)
  const int bh = virt >> 4, qb = virt & 15;
  const int q0 = qb * TQ;
  const int t = threadIdx.x, lane = t & 63, w = t >> 6;
  const int l31 = lane & 31, hi = lane >> 5;
  const int wq = w & 3, kh = w >> 2;              // q-subblock, k-half

  const float* kbh = k + (size_t)bh * S_LEN * D_DIM;
  const float* vbh = v + (size_t)bh * S_LEN * D_DIM;
  const float* qbh = q + (size_t)bh * S_LEN * D_DIM;

  // staging ownership
  const int kr = t >> 3, kc = t & 7;              // K/G: row, 8-float col group
  const int vr = (t & 31) * 2, vc = (t >> 5) * 4; // V: row pair, 4-col group

  // ---- prefetch tile 0 (K,V) into registers ----
  float4 pk0, pk1, pva, pvb;
  {
    const float4* kp_ = (const float4*)(kbh + (size_t)kr * D_DIM + kc * 8);
    pk0 = kp_[0]; pk1 = kp_[1];
    const float4* vp0 = (const float4*)(vbh + (size_t)vr * D_DIM + vc);
    const float4* vp1 = (const float4*)(vbh + (size_t)(vr + 1) * D_DIM + vc);
    pva = vp0[0]; pvb = vp1[0];
  }

  // ---- Q A-fragments, 32-shape: lane holds Q[q0+wq*32+l31][s*16+hi*8 .. +7] ----
  bf8_t qA[4];
  {
    const float* qrow = qbh + (size_t)(q0 + wq * 32 + l31) * D_DIM;
#pragma unroll
    for (int s = 0; s < 4; ++s) {
      const float4* qp = (const float4*)(qrow + s * 16 + hi * 8);
      float4 a = qp[0], b = qp[1];
      u4bf8 x;
      x.u[0] = cvtpk(a.x * SCALE_F, a.y * SCALE_F);
      x.u[1] = cvtpk(a.z * SCALE_F, a.w * SCALE_F);
      x.u[2] = cvtpk(b.x * SCALE_F, b.y * SCALE_F);
      x.u[3] = cvtpk(b.z * SCALE_F, b.w * SCALE_F);
      qA[s] = x.b;
    }
  }

  // ---- stage G = sum of 4 partials (bf16, swizzled) into sK buf0 ----
  {
    const float* gp = gpart + ((size_t)bh << 12) + (size_t)kr * D_DIM + kc * 8;
    const size_t gstride = (size_t)NBH << 12;
    float4 a = {0.f, 0.f, 0.f, 0.f}, b = {0.f, 0.f, 0.f, 0.f};
#pragma unroll
    for (int rc = 0; rc < RC_G; ++rc) {
      const float4* p = (const float4*)(gp + rc * gstride);
      float4 x = p[0], y = p[1];
      a.x += x.x; a.y += x.y; a.z += x.z; a.w += x.w;
      b.x += y.x; b.y += y.y; b.z += y.z; b.w += y.w;
    }
    u4bf8 x;
    x.u[0] = cvtpk(a.x, a.y); x.u[1] = cvtpk(a.z, a.w);
    x.u[2] = cvtpk(b.x, b.y); x.u[3] = cvtpk(b.z, b.w);
    *(u4_t*)(sK + kr * 64 + ((kc ^ (kr & 7)) << 3)) = x.u;
  }
  __syncthreads();

  // ---- den via verified 16-shape path, bridged through sInv ----
  {
    const int lr = lane & 15, lh = lane >> 4;
    bf8_t qD[2];
    {
      const float* qbase = qbh + (size_t)(q0 + w * 16 + lr) * D_DIM;
#pragma unroll
      for (int h2 = 0; h2 < 2; ++h2) {
        const float4* qp = (const float4*)(qbase + h2 * 32 + lh * 8);
        float4 a = qp[0], b = qp[1];
        u4bf8 x;
        x.u[0] = cvtpk(a.x * SCALE_F, a.y * SCALE_F);
        x.u[1] = cvtpk(a.z * SCALE_F, a.w * SCALE_F);
        x.u[2] = cvtpk(b.x * SCALE_F, b.y * SCALE_F);
        x.u[3] = cvtpk(b.z * SCALE_F, b.w * SCALE_F);
        qD[h2] = x.b;
      }
    }
    float den[4] = {0.f, 0.f, 0.f, 0.f};
#pragma unroll
    for (int ct = 0; ct < 4; ++ct) {
      f4_t accT = {0.f, 0.f, 0.f, 0.f};
      bf8_t b0 = frag_swz(sK, ct * 16 + lr, lh);
      bf8_t b1 = frag_swz(sK, ct * 16 + lr, 4 + lh);
      accT = MFMA16(qD[0], b0, accT);
      accT = MFMA16(qD[1], b1, accT);
#pragma unroll
      for (int i = 0; i < 4; ++i) {
        float qv = qbh[(size_t)(q0 + w * 16 + lh * 4 + i) * D_DIM + ct * 16 + lr] * SCALE_F;
        den[i] += accT[i] * qv;
      }
    }
#pragma unroll
    for (int i = 0; i < 4; ++i) {
      den[i] += __shfl_xor(den[i], 1, 64);
      den[i] += __shfl_xor(den[i], 2, 64);
      den[i] += __shfl_xor(den[i], 4, 64);
      den[i] += __shfl_xor(den[i], 8, 64);
      sInv[w * 16 + lh * 4 + i] = 1.f / (den[i] + EPS_F);
    }
  }
  __syncthreads();

  // reload inv per 32-shape C mapping: reg r -> q row (r&3)+8*(r>>2)+4*hi
  float invv[16];
#pragma unroll
  for (int r = 0; r < 16; ++r)
    invv[r] = sInv[wq * 32 + (r & 3) + 8 * (r >> 2) + 4 * hi];
  __syncthreads();   // sInv reads done; sK(G) reads done

  // ---- write tile 0 into buffer 0 ----
  {
    u4bf8 x;
    x.u[0] = cvtpk(pk0.x, pk0.y); x.u[1] = cvtpk(pk0.z, pk0.w);
    x.u[2] = cvtpk(pk1.x, pk1.y); x.u[3] = cvtpk(pk1.z, pk1.w);
    *(u4_t*)(sK + kr * 64 + ((kc ^ (kr & 7)) << 3)) = x.u;
    unsigned int w0 = cvtpk(pva.x, pvb.x), w1 = cvtpk(pva.y, pvb.y);
    unsigned int w2 = cvtpk(pva.z, pvb.z), w3 = cvtpk(pva.w, pvb.w);
    const int cks = vr >> 3, sub = vr & 7;
    *(unsigned int*)(sVt + (vc + 0) * 64 + ((cks ^ ((vc + 0) & 7)) << 3) + sub) = w0;
    *(unsigned int*)(sVt + (vc + 1) * 64 + ((cks ^ ((vc + 1) & 7)) << 3) + sub) = w1;
    *(unsigned int*)(sVt + (vc + 2) * 64 + ((cks ^ ((vc + 2) & 7)) << 3) + sub) = w2;
    *(unsigned int*)(sVt + (vc + 3) * 64 + ((cks ^ ((vc + 3) & 7)) << 3) + sub) = w3;
  }
  __syncthreads();

  f16_t oaccA, oaccB;
#pragma unroll
  for (int i = 0; i < 16; ++i) { oaccA[i] = 0.f; oaccB[i] = 0.f; }

  us* sPw = sP + w * (32 * SPSTR);                // per-wave 32 x SPSTR shorts
  float* probw = probp + ((size_t)bh * S_LEN + q0 + wq * 32) * S_LEN + kh * 32 + l31;

  for (int kt = 0; kt < NT; ++kt) {
    const int cur = kt & 1, nxt = cur ^ 1;
    const us* sKc = sK + cur * 4096;
    const us* sVc = sVt + cur * 4096;
    us* sKn = sK + nxt * 4096;
    us* sVn = sVt + nxt * 4096;
    const int k0 = kt * KT;

    // ---- issue next tile's global loads FIRST (latency hides under compute) ----
    if (kt + 1 < NT) {
      const int k0n = k0 + KT;
      const float4* kp_ = (const float4*)(kbh + (size_t)(k0n + kr) * D_DIM + kc * 8);
      pk0 = kp_[0]; pk1 = kp_[1];
      const float4* vp0 = (const float4*)(vbh + (size_t)(k0n + vr) * D_DIM + vc);
      const float4* vp1 = (const float4*)(vbh + (size_t)(k0n + vr + 1) * D_DIM + vc);
      pva = vp0[0]; pvb = vp1[0];
    }

    // ---- V B-frags (hoisted: independent of QK/prob) ----
    bf8_t vb00 = frag_swz(sVc, 0 * 32 + l31, kh * 4 + 2 * 0 + hi);
    bf8_t vb01 = frag_swz(sVc, 1 * 32 + l31, kh * 4 + 2 * 0 + hi);
    bf8_t vb10 = frag_swz(sVc, 0 * 32 + l31, kh * 4 + 2 * 1 + hi);
    bf8_t vb11 = frag_swz(sVc, 1 * 32 + l31, kh * 4 + 2 * 1 + hi);

    // ---- QK^T (32-shape): C = 32q x 32k for this wave's k-half ----
    f16_t cacc;
#pragma unroll
    for (int i = 0; i < 16; ++i) cacc[i] = 0.f;
    __builtin_amdgcn_s_setprio(1);
#pragma unroll
    for (int s = 0; s < 4; ++s) {
      bf8_t bk = frag_swz(sKc, kh * 32 + l31, 2 * s + hi);
      cacc = MFMA32(qA[s], bk, cacc);
    }
    __builtin_amdgcn_s_setprio(0);

    // ---- prob = s^2 * inv: NT store fp32 + bf16 row-major into sP ----
#pragma unroll
    for (int a = 0; a < 4; ++a) {
      float p0 = cacc[4 * a + 0] * cacc[4 * a + 0] * invv[4 * a + 0];
      float p1 = cacc[4 * a + 1] * cacc[4 * a + 1] * invv[4 * a + 1];
      float p2 = cacc[4 * a + 2] * cacc[4 * a + 2] * invv[4 * a + 2];
      float p3 = cacc[4 * a + 3] * cacc[4 * a + 3] * invv[4 * a + 3];
      const int qq = 8 * a + 4 * hi;
      __builtin_nontemporal_store(p0, probw + (size_t)(qq + 0) * S_LEN + k0);
      __builtin_nontemporal_store(p1, probw + (size_t)(qq + 1) * S_LEN + k0);
      __builtin_nontemporal_store(p2, probw + (size_t)(qq + 2) * S_LEN + k0);
      __builtin_nontemporal_store(p3, probw + (size_t)(qq + 3) * S_LEN + k0);
      unsigned int c01 = cvtpk(p0, p1);
      unsigned int c23 = cvtpk(p2, p3);
      sPw[(qq + 0) * SPSTR + l31] = (us)(c01 & 0xffffu);
      sPw[(qq + 1) * SPSTR + l31] = (us)(c01 >> 16);
      sPw[(qq + 2) * SPSTR + l31] = (us)(c23 & 0xffffu);
      sPw[(qq + 3) * SPSTR + l31] = (us)(c23 >> 16);
    }

    // ---- PV A-frags: plain b128 reads of P rows (same-wave, compiler-ordered) ----
    bf8_t pa0 = *(const bf8_t*)(sPw + l31 * SPSTR + 0 * 16 + hi * 8);
    bf8_t pa1 = *(const bf8_t*)(sPw + l31 * SPSTR + 1 * 16 + hi * 8);

    __builtin_amdgcn_s_setprio(1);
    oaccA = MFMA32(pa0, vb00, oaccA);
    oaccB = MFMA32(pa0, vb01, oaccB);
    oaccA = MFMA32(pa1, vb10, oaccA);
    oaccB = MFMA32(pa1, vb11, oaccB);
    __builtin_amdgcn_s_setprio(0);

    // ---- write prefetched tile kt+1 into the other buffer, then ONE barrier ----
    if (kt + 1 < NT) {
      u4bf8 x;
      x.u[0] = cvtpk(pk0.x, pk0.y); x.u[1] = cvtpk(pk0.z, pk0.w);
      x.u[2] = cvtpk(pk1.x, pk1.y); x.u[3] = cvtpk(pk1.z, pk1.w);
      *(u4_t*)(sKn + kr * 64 + ((kc ^ (kr & 7)) << 3)) = x.u;
      unsigned int w0 = cvtpk(pva.x, pvb.x), w1 = cvtpk(pva.y, pvb.y);
      unsigned int w2 = cvtpk(pva.z, pvb.z), w3 = cvtpk(pva.w, pvb.w);
      const int cks = vr >> 3, sub = vr & 7;
      *(unsigned int*)(sVn + (vc + 0) * 64 + ((cks ^ ((vc + 0) & 7)) << 3) + sub) = w0;
      *(unsigned int*)(sVn + (vc + 1) * 64 + ((cks ^ ((vc + 1) & 7)) << 3) + sub) = w1;
      *(unsigned int*)(sVn + (vc + 2) * 64 + ((cks ^ ((vc + 2) & 7)) << 3) + sub) = w2;
      *(unsigned int*)(sVn + (vc + 3) * 64 + ((cks ^ ((vc + 3) & 7)) << 3) + sub) = w3;
    }
    __syncthreads();
  }

  // ---- k-half reduction + out store ----
  if (kh == 1) {
    float* dst = sRed + wq * 2048;
#pragma unroll
    for (int i = 0; i < 4; ++i) {
      f4_t ga = {oaccA[4 * i], oaccA[4 * i + 1], oaccA[4 * i + 2], oaccA[4 * i + 3]};
      f4_t gb = {oaccB[4 * i], oaccB[4 * i + 1], oaccB[4 * i + 2], oaccB[4 * i + 3]};
      *(f4_t*)(dst + 0 * 1024 + i * 256 + lane * 4) = ga;
      *(f4_t*)(dst + 1 * 1024 + i * 256 + lane * 4) = gb;
    }
  }
  __syncthreads();
  if (kh == 0) {
    const float* src = sRed + wq * 2048;
    float* ob = outp + ((size_t)bh * S_LEN + q0 + wq * 32) * D_DIM + l31;
#pragma unroll
    for (int i = 0; i < 4; ++i) {
      f4_t ga = *(const f4_t*)(src + 0 * 1024 + i * 256 + lane * 4);
      f4_t gb = *(const f4_t*)(src + 1 * 1024 + i * 256 + lane * 4);
#pragma unroll
      for (int b = 0; b < 4; ++b) {
        const int r = 4 * i + b;
        const int qr = (r & 3) + 8 * (r >> 2) + 4 * hi;
        __builtin_nontemporal_store(oaccA[r] + ga[b], ob + (size_t)qr * D_DIM + 0);
        __builtin_nontemporal_store(oaccB[r] + gb[b], ob + (size_t)qr * D_DIM + 32);
      }
    }
  }
}

extern "C" void kernel_launch(void* const* d_in, const int* in_sizes, int n_in,
                              void* d_out, int out_size, void* d_ws, size_t ws_size,
                              hipStream_t stream) {
  (void)in_sizes; (void)n_in; (void)out_size; (void)ws_size;
  const float* q = (const float*)d_in[0];
  const float* k = (const float*)d_in[1];
  const float* v = (const float*)d_in[2];
  float* outp  = (float*)d_out;
  float* probp = outp + (size_t)NBH * S_LEN * D_DIM;
  float* gpart = (float*)d_ws;   // RC_G * NBH * 4096 floats = 2 MB

  g_kernel<<<dim3(NBH * RC_G), dim3(256), 0, stream>>>(k, gpart);
  attn_main<<<dim3(512), dim3(512), 0, stream>>>(q, k, v, gpart, outp, probp);
}

// Round 7
// 138.817 us; speedup vs baseline: 1.4505x; 1.4505x over previous
//
#include <hip/hip_runtime.h>
#include <stdint.h>

#define S_LEN 2048
#define D_DIM 64
#define NBH   32
#define TQ    128
#define KT    64
#define NT    (S_LEN / KT)
#define RC_G  8
#define SCALE_F 0.125f
#define EPS_F   1e-6f
#define SPSTR 40   /* sP row stride in shorts: 80B, 16B-aligned rows */

typedef unsigned short us;
typedef __attribute__((ext_vector_type(8))) short bf8_t;
typedef __attribute__((ext_vector_type(4))) float f4_t;
typedef __attribute__((ext_vector_type(16))) float f16_t;
typedef __attribute__((ext_vector_type(4))) unsigned int u4_t;

#define MFMA16(a,b,c) __builtin_amdgcn_mfma_f32_16x16x32_bf16((a),(b),(c),0,0,0)
#define MFMA32(a,b,c) __builtin_amdgcn_mfma_f32_32x32x16_bf16((a),(b),(c),0,0,0)

__device__ __forceinline__ unsigned int cvtpk(float lo, float hi) {
  unsigned int d;
  asm("v_cvt_pk_bf16_f32 %0, %1, %2" : "=v"(d) : "v"(lo), "v"(hi));
  return d;
}

union u4bf8 { u4_t u; bf8_t b; };

// ---------------- G partials: gpart[rc][bh][64*64], no atomics, 256 blocks ----------------
__global__ __launch_bounds__(256) void g_kernel(const float* __restrict__ kp,
                                                float* __restrict__ gpart) {
  __shared__ __align__(16) float sk[64][68];
  const int bh = blockIdx.x >> 3, rc = blockIdx.x & 7;
  const int t = threadIdx.x;
  const int ti = t >> 4, tj = t & 15;   // tj fast => coalesced stores
  float acc[4][4];
#pragma unroll
  for (int a = 0; a < 4; ++a)
#pragma unroll
    for (int b = 0; b < 4; ++b) acc[a][b] = 0.f;
  const float* kb = kp + ((size_t)bh * S_LEN + rc * 256) * D_DIM;
  for (int sub = 0; sub < 4; ++sub) {
    __syncthreads();
    {
      const int r = t >> 2, c0 = (t & 3) * 16;
      const float4* p = (const float4*)(kb + (size_t)(sub * 64 + r) * D_DIM + c0);
      float4 x0 = p[0], x1 = p[1], x2 = p[2], x3 = p[3];
      *(float4*)&sk[r][c0]      = x0;
      *(float4*)&sk[r][c0 + 4]  = x1;
      *(float4*)&sk[r][c0 + 8]  = x2;
      *(float4*)&sk[r][c0 + 12] = x3;
    }
    __syncthreads();
#pragma unroll 4
    for (int r = 0; r < 64; ++r) {
      float4 qi = *(const float4*)&sk[r][ti * 4];
      float4 qj = *(const float4*)&sk[r][tj * 4];
      float iv[4] = {qi.x, qi.y, qi.z, qi.w};
      float jv[4] = {qj.x, qj.y, qj.z, qj.w};
#pragma unroll
      for (int a = 0; a < 4; ++a)
#pragma unroll
        for (int b = 0; b < 4; ++b) acc[a][b] += iv[a] * jv[b];
    }
  }
  float* gb = gpart + ((size_t)(rc * NBH + bh) << 12);
#pragma unroll
  for (int a = 0; a < 4; ++a) {
    f4_t vv = {acc[a][0], acc[a][1], acc[a][2], acc[a][3]};
    *(f4_t*)(gb + (ti * 4 + a) * 64 + tj * 4) = vv;
  }
}

// swizzled row-major bf16 tile: row stride 64 shorts, 16B chunks XOR'd by row&7
__device__ __forceinline__ bf8_t frag_swz(const us* sp, int row, int cb) {
  return *(const bf8_t*)(sp + row * 64 + ((cb ^ (row & 7)) << 3));
}

// ---------------- main attention kernel ----------------
__global__ __launch_bounds__(512, 4) void attn_main(const float* __restrict__ q,
                                                    const float* __restrict__ k,
                                                    const float* __restrict__ v,
                                                    const float* __restrict__ gpart,
                                                    float* __restrict__ outp,
                                                    float* __restrict__ probp) {
  // smem: sK 2x8KB | sVt 2x8KB | sP 8 waves * 2560B = 20480B  (total 53248)
  // sInv(512B) overlaps sP start (used only before main loop)
  // sRed(32KB) overlaps sK (used only in epilogue)
  __shared__ __align__(16) unsigned char smem[53248];
  us* sK  = (us*)smem;                 // 2 buffers of 4096 shorts
  us* sVt = (us*)(smem + 16384);       // 2 buffers of 4096 shorts
  us* sP  = (us*)(smem + 32768);
  float* sInv = (float*)(smem + 32768);
  float* sRed = (float*)smem;

  const int lin = blockIdx.x;
  const int virt = (lin & 7) * 64 + (lin >> 3);   // XCD swizzle (512 = 8*64)
  const int bh = virt >> 4, qb = virt & 15;
  const int q0 = qb * TQ;
  const int t = threadIdx.x, lane = t & 63, w = t >> 6;
  const int l31 = lane & 31, hi = lane >> 5;
  const int wq = w & 3, kh = w >> 2;              // q-subblock, k-half

  const float* kbh = k + (size_t)bh * S_LEN * D_DIM;
  const float* vbh = v + (size_t)bh * S_LEN * D_DIM;
  const float* qbh = q + (size_t)bh * S_LEN * D_DIM;

  // staging ownership
  const int kr = t >> 3, kc = t & 7;              // K/G: row, 8-float col group
  const int vr = (t & 31) * 2, vc = (t >> 5) * 4; // V: row pair, 4-col group

  // ---- prefetch tile 0 (K,V) into registers ----
  float4 pk0, pk1, pva, pvb;
  {
    const float4* kp_ = (const float4*)(kbh + (size_t)kr * D_DIM + kc * 8);
    pk0 = kp_[0]; pk1 = kp_[1];
    const float4* vp0 = (const float4*)(vbh + (size_t)vr * D_DIM + vc);
    const float4* vp1 = (const float4*)(vbh + (size_t)(vr + 1) * D_DIM + vc);
    pva = vp0[0]; pvb = vp1[0];
  }

  // ---- Q A-fragments, 32-shape: lane holds Q[q0+wq*32+l31][s*16+hi*8 .. +7] ----
  bf8_t qA[4];
  {
    const float* qrow = qbh + (size_t)(q0 + wq * 32 + l31) * D_DIM;
#pragma unroll
    for (int s = 0; s < 4; ++s) {
      const float4* qp = (const float4*)(qrow + s * 16 + hi * 8);
      float4 a = qp[0], b = qp[1];
      u4bf8 x;
      x.u[0] = cvtpk(a.x * SCALE_F, a.y * SCALE_F);
      x.u[1] = cvtpk(a.z * SCALE_F, a.w * SCALE_F);
      x.u[2] = cvtpk(b.x * SCALE_F, b.y * SCALE_F);
      x.u[3] = cvtpk(b.z * SCALE_F, b.w * SCALE_F);
      qA[s] = x.b;
    }
  }

  // ---- stage G = sum of RC_G partials (bf16, swizzled) into sK buf0 ----
  {
    const float* gp = gpart + ((size_t)bh << 12) + (size_t)kr * D_DIM + kc * 8;
    const size_t gstride = (size_t)NBH << 12;
    float4 a = {0.f, 0.f, 0.f, 0.f}, b = {0.f, 0.f, 0.f, 0.f};
#pragma unroll
    for (int rc = 0; rc < RC_G; ++rc) {
      const float4* p = (const float4*)(gp + rc * gstride);
      float4 x = p[0], y = p[1];
      a.x += x.x; a.y += x.y; a.z += x.z; a.w += x.w;
      b.x += y.x; b.y += y.y; b.z += y.z; b.w += y.w;
    }
    u4bf8 x;
    x.u[0] = cvtpk(a.x, a.y); x.u[1] = cvtpk(a.z, a.w);
    x.u[2] = cvtpk(b.x, b.y); x.u[3] = cvtpk(b.z, b.w);
    *(u4_t*)(sK + kr * 64 + ((kc ^ (kr & 7)) << 3)) = x.u;
  }
  __syncthreads();

  // ---- den via verified 16-shape path, bridged through sInv ----
  {
    const int lr = lane & 15, lh = lane >> 4;
    bf8_t qD[2];
    {
      const float* qbase = qbh + (size_t)(q0 + w * 16 + lr) * D_DIM;
#pragma unroll
      for (int h2 = 0; h2 < 2; ++h2) {
        const float4* qp = (const float4*)(qbase + h2 * 32 + lh * 8);
        float4 a = qp[0], b = qp[1];
        u4bf8 x;
        x.u[0] = cvtpk(a.x * SCALE_F, a.y * SCALE_F);
        x.u[1] = cvtpk(a.z * SCALE_F, a.w * SCALE_F);
        x.u[2] = cvtpk(b.x * SCALE_F, b.y * SCALE_F);
        x.u[3] = cvtpk(b.z * SCALE_F, b.w * SCALE_F);
        qD[h2] = x.b;
      }
    }
    float den[4] = {0.f, 0.f, 0.f, 0.f};
#pragma unroll
    for (int ct = 0; ct < 4; ++ct) {
      f4_t accT = {0.f, 0.f, 0.f, 0.f};
      bf8_t b0 = frag_swz(sK, ct * 16 + lr, lh);
      bf8_t b1 = frag_swz(sK, ct * 16 + lr, 4 + lh);
      accT = MFMA16(qD[0], b0, accT);
      accT = MFMA16(qD[1], b1, accT);
#pragma unroll
      for (int i = 0; i < 4; ++i) {
        float qv = qbh[(size_t)(q0 + w * 16 + lh * 4 + i) * D_DIM + ct * 16 + lr] * SCALE_F;
        den[i] += accT[i] * qv;
      }
    }
#pragma unroll
    for (int i = 0; i < 4; ++i) {
      den[i] += __shfl_xor(den[i], 1, 64);
      den[i] += __shfl_xor(den[i], 2, 64);
      den[i] += __shfl_xor(den[i], 4, 64);
      den[i] += __shfl_xor(den[i], 8, 64);
      sInv[w * 16 + lh * 4 + i] = 1.f / (den[i] + EPS_F);
    }
  }
  __syncthreads();

  // reload inv per 32-shape C mapping: reg r -> q row (r&3)+8*(r>>2)+4*hi
  float invv[16];
#pragma unroll
  for (int r = 0; r < 16; ++r)
    invv[r] = sInv[wq * 32 + (r & 3) + 8 * (r >> 2) + 4 * hi];
  __syncthreads();   // sInv reads done; sK(G) reads done

  // ---- write tile 0 into buffer 0 ----
  {
    u4bf8 x;
    x.u[0] = cvtpk(pk0.x, pk0.y); x.u[1] = cvtpk(pk0.z, pk0.w);
    x.u[2] = cvtpk(pk1.x, pk1.y); x.u[3] = cvtpk(pk1.z, pk1.w);
    *(u4_t*)(sK + kr * 64 + ((kc ^ (kr & 7)) << 3)) = x.u;
    unsigned int w0 = cvtpk(pva.x, pvb.x), w1 = cvtpk(pva.y, pvb.y);
    unsigned int w2 = cvtpk(pva.z, pvb.z), w3 = cvtpk(pva.w, pvb.w);
    const int cks = vr >> 3, sub = vr & 7;
    *(unsigned int*)(sVt + (vc + 0) * 64 + ((cks ^ ((vc + 0) & 7)) << 3) + sub) = w0;
    *(unsigned int*)(sVt + (vc + 1) * 64 + ((cks ^ ((vc + 1) & 7)) << 3) + sub) = w1;
    *(unsigned int*)(sVt + (vc + 2) * 64 + ((cks ^ ((vc + 2) & 7)) << 3) + sub) = w2;
    *(unsigned int*)(sVt + (vc + 3) * 64 + ((cks ^ ((vc + 3) & 7)) << 3) + sub) = w3;
  }
  __syncthreads();

  f16_t oaccA, oaccB;
#pragma unroll
  for (int i = 0; i < 16; ++i) { oaccA[i] = 0.f; oaccB[i] = 0.f; }

  us* sPw = sP + w * (32 * SPSTR);                // per-wave 32 x SPSTR shorts
  float* probw = probp + ((size_t)bh * S_LEN + q0 + wq * 32) * S_LEN + kh * 32 + l31;

  for (int kt = 0; kt < NT; ++kt) {
    const int cur = kt & 1, nxt = cur ^ 1;
    const us* sKc = sK + cur * 4096;
    const us* sVc = sVt + cur * 4096;
    us* sKn = sK + nxt * 4096;
    us* sVn = sVt + nxt * 4096;
    const int k0 = kt * KT;

    // ---- issue next tile's global loads FIRST (latency hides under compute) ----
    if (kt + 1 < NT) {
      const int k0n = k0 + KT;
      const float4* kp_ = (const float4*)(kbh + (size_t)(k0n + kr) * D_DIM + kc * 8);
      pk0 = kp_[0]; pk1 = kp_[1];
      const float4* vp0 = (const float4*)(vbh + (size_t)(k0n + vr) * D_DIM + vc);
      const float4* vp1 = (const float4*)(vbh + (size_t)(k0n + vr + 1) * D_DIM + vc);
      pva = vp0[0]; pvb = vp1[0];
    }

    // ---- QK^T (32-shape): C = 32q x 32k for this wave's k-half ----
    f16_t cacc;
#pragma unroll
    for (int i = 0; i < 16; ++i) cacc[i] = 0.f;
#pragma unroll
    for (int s = 0; s < 4; ++s) {
      bf8_t bk = frag_swz(sKc, kh * 32 + l31, 2 * s + hi);
      cacc = MFMA32(qA[s], bk, cacc);
    }

    // ---- prob = s^2 * inv: NT store fp32 + bf16 row-major into sP ----
#pragma unroll
    for (int a = 0; a < 4; ++a) {
      float p0 = cacc[4 * a + 0] * cacc[4 * a + 0] * invv[4 * a + 0];
      float p1 = cacc[4 * a + 1] * cacc[4 * a + 1] * invv[4 * a + 1];
      float p2 = cacc[4 * a + 2] * cacc[4 * a + 2] * invv[4 * a + 2];
      float p3 = cacc[4 * a + 3] * cacc[4 * a + 3] * invv[4 * a + 3];
      const int qq = 8 * a + 4 * hi;
      __builtin_nontemporal_store(p0, probw + (size_t)(qq + 0) * S_LEN + k0);
      __builtin_nontemporal_store(p1, probw + (size_t)(qq + 1) * S_LEN + k0);
      __builtin_nontemporal_store(p2, probw + (size_t)(qq + 2) * S_LEN + k0);
      __builtin_nontemporal_store(p3, probw + (size_t)(qq + 3) * S_LEN + k0);
      unsigned int c01 = cvtpk(p0, p1);
      unsigned int c23 = cvtpk(p2, p3);
      sPw[(qq + 0) * SPSTR + l31] = (us)(c01 & 0xffffu);
      sPw[(qq + 1) * SPSTR + l31] = (us)(c01 >> 16);
      sPw[(qq + 2) * SPSTR + l31] = (us)(c23 & 0xffffu);
      sPw[(qq + 3) * SPSTR + l31] = (us)(c23 >> 16);
    }

    // ---- PV A-frags: plain b128 reads of P rows (same-wave, compiler-ordered) ----
    bf8_t pa0 = *(const bf8_t*)(sPw + l31 * SPSTR + 0 * 16 + hi * 8);
    bf8_t pa1 = *(const bf8_t*)(sPw + l31 * SPSTR + 1 * 16 + hi * 8);

    // ---- V B-frags from current buffer ----
    bf8_t vb00 = frag_swz(sVc, 0 * 32 + l31, kh * 4 + 2 * 0 + hi);
    bf8_t vb01 = frag_swz(sVc, 1 * 32 + l31, kh * 4 + 2 * 0 + hi);
    bf8_t vb10 = frag_swz(sVc, 0 * 32 + l31, kh * 4 + 2 * 1 + hi);
    bf8_t vb11 = frag_swz(sVc, 1 * 32 + l31, kh * 4 + 2 * 1 + hi);

    oaccA = MFMA32(pa0, vb00, oaccA);
    oaccB = MFMA32(pa0, vb01, oaccB);
    oaccA = MFMA32(pa1, vb10, oaccA);
    oaccB = MFMA32(pa1, vb11, oaccB);

    // ---- write prefetched tile kt+1 into the other buffer, then ONE barrier ----
    if (kt + 1 < NT) {
      u4bf8 x;
      x.u[0] = cvtpk(pk0.x, pk0.y); x.u[1] = cvtpk(pk0.z, pk0.w);
      x.u[2] = cvtpk(pk1.x, pk1.y); x.u[3] = cvtpk(pk1.z, pk1.w);
      *(u4_t*)(sKn + kr * 64 + ((kc ^ (kr & 7)) << 3)) = x.u;
      unsigned int w0 = cvtpk(pva.x, pvb.x), w1 = cvtpk(pva.y, pvb.y);
      unsigned int w2 = cvtpk(pva.z, pvb.z), w3 = cvtpk(pva.w, pvb.w);
      const int cks = vr >> 3, sub = vr & 7;
      *(unsigned int*)(sVn + (vc + 0) * 64 + ((cks ^ ((vc + 0) & 7)) << 3) + sub) = w0;
      *(unsigned int*)(sVn + (vc + 1) * 64 + ((cks ^ ((vc + 1) & 7)) << 3) + sub) = w1;
      *(unsigned int*)(sVn + (vc + 2) * 64 + ((cks ^ ((vc + 2) & 7)) << 3) + sub) = w2;
      *(unsigned int*)(sVn + (vc + 3) * 64 + ((cks ^ ((vc + 3) & 7)) << 3) + sub) = w3;
    }
    __syncthreads();
  }

  // ---- k-half reduction + out store ----
  if (kh == 1) {
    float* dst = sRed + wq * 2048;
#pragma unroll
    for (int i = 0; i < 4; ++i) {
      f4_t ga = {oaccA[4 * i], oaccA[4 * i + 1], oaccA[4 * i + 2], oaccA[4 * i + 3]};
      f4_t gb = {oaccB[4 * i], oaccB[4 * i + 1], oaccB[4 * i + 2], oaccB[4 * i + 3]};
      *(f4_t*)(dst + 0 * 1024 + i * 256 + lane * 4) = ga;
      *(f4_t*)(dst + 1 * 1024 + i * 256 + lane * 4) = gb;
    }
  }
  __syncthreads();
  if (kh == 0) {
    const float* src = sRed + wq * 2048;
    float* ob = outp + ((size_t)bh * S_LEN + q0 + wq * 32) * D_DIM + l31;
#pragma unroll
    for (int i = 0; i < 4; ++i) {
      f4_t ga = *(const f4_t*)(src + 0 * 1024 + i * 256 + lane * 4);
      f4_t gb = *(const f4_t*)(src + 1 * 1024 + i * 256 + lane * 4);
#pragma unroll
      for (int b = 0; b < 4; ++b) {
        const int r = 4 * i + b;
        const int qr = (r & 3) + 8 * (r >> 2) + 4 * hi;
        __builtin_nontemporal_store(oaccA[r] + ga[b], ob + (size_t)qr * D_DIM + 0);
        __builtin_nontemporal_store(oaccB[r] + gb[b], ob + (size_t)qr * D_DIM + 32);
      }
    }
  }
}

extern "C" void kernel_launch(void* const* d_in, const int* in_sizes, int n_in,
                              void* d_out, int out_size, void* d_ws, size_t ws_size,
                              hipStream_t stream) {
  (void)in_sizes; (void)n_in; (void)out_size; (void)ws_size;
  const float* q = (const float*)d_in[0];
  const float* k = (const float*)d_in[1];
  const float* v = (const float*)d_in[2];
  float* outp  = (float*)d_out;
  float* probp = outp + (size_t)NBH * S_LEN * D_DIM;
  float* gpart = (float*)d_ws;   // RC_G * NBH * 4096 floats = 4 MB

  g_kernel<<<dim3(NBH * RC_G), dim3(256), 0, stream>>>(k, gpart);
  attn_main<<<dim3(512), dim3(512), 0, stream>>>(q, k, v, gpart, outp, probp);
}